// Round 1
// baseline (1684.295 us; speedup 1.0000x reference)
//
#include <hip/hip_runtime.h>
#include <hip/hip_bf16.h>
#include <hip/hip_fp16.h>

#define D 512

typedef _Float16 half8 __attribute__((ext_vector_type(8)));
typedef _Float16 half4v __attribute__((ext_vector_type(4)));
typedef float floatx4 __attribute__((ext_vector_type(4)));

// ---------------- conversion kernels ----------------

__global__ void k_f32_to_f16(const float* __restrict__ in, _Float16* __restrict__ out, int n4) {
  int i = blockIdx.x * blockDim.x + threadIdx.x;
  if (i >= n4) return;
  float4 v = ((const float4*)in)[i];
  half4v h;
  h.x = (_Float16)v.x; h.y = (_Float16)v.y; h.z = (_Float16)v.z; h.w = (_Float16)v.w;
  ((half4v*)out)[i] = h;
}

// wT[jg][k] = w_m[k][j],  jg = m*512 + j  (B^T layout for MFMA)
__global__ void k_build_wt(const float* __restrict__ w1, const float* __restrict__ w2,
                           const float* __restrict__ w3, _Float16* __restrict__ wT) {
  int id = blockIdx.x * blockDim.x + threadIdx.x;
  if (id >= 3 * D * D) return;
  int jg = id >> 9;
  int k  = id & (D - 1);
  const float* w = (jg < D) ? w1 : (jg < 2 * D ? w2 : w3);
  int j = jg & (D - 1);
  wT[id] = (_Float16)w[k * D + j];
}

// ---------------- CSR build ----------------

__global__ void k_count(const int* __restrict__ row, int* __restrict__ counts, int E) {
  int i = blockIdx.x * blockDim.x + threadIdx.x;
  if (i < E) atomicAdd(&counts[row[i]], 1);
}

// single-block exclusive scan: wave shfl scan + block combine, 1024 threads
__global__ void k_scan(const int* __restrict__ counts, int* __restrict__ offsets, int n) {
  __shared__ int wsum[16];
  __shared__ int s_carry;
  int tid = threadIdx.x;
  int lane = tid & 63, wid = tid >> 6;
  if (tid == 0) s_carry = 0;
  __syncthreads();
  for (int base = 0; base < n; base += 1024) {
    int i = base + tid;
    int c = (i < n) ? counts[i] : 0;
    int x = c;
#pragma unroll
    for (int o = 1; o < 64; o <<= 1) {
      int v = __shfl_up(x, o);
      if (lane >= o) x += v;
    }
    if (lane == 63) wsum[wid] = x;
    __syncthreads();
    int wpre = 0;
    for (int w = 0; w < wid; ++w) wpre += wsum[w];
    if (i < n) offsets[i] = s_carry + wpre + (x - c);
    __syncthreads();
    if (tid == 0) {
      int tot = 0;
#pragma unroll
      for (int w = 0; w < 16; ++w) tot += wsum[w];
      s_carry += tot;
    }
    __syncthreads();
  }
  if (tid == 0) offsets[n] = s_carry;
}

__global__ void k_scatter(const int* __restrict__ row, const int* __restrict__ col,
                          const float* __restrict__ val, const int* __restrict__ offsets,
                          int* __restrict__ cursor, int2* __restrict__ edges, int E) {
  int i = blockIdx.x * blockDim.x + threadIdx.x;
  if (i >= E) return;
  int r = row[i];
  int p = offsets[r] + atomicAdd(&cursor[r], 1);
  edges[p] = make_int2(col[i], __float_as_int(val[i]));
}

// ---------------- fused triple GEMM ----------------
// C = x @ [w1 | w2 | w3]; epilogues: support=f16(no bias), trans=+b2 (fp32 -> d_out),
// gate=sigmoid(+b3) (f16). 128x128 tile, 4 waves each 64x64 (4x4 MFMA frags).
__global__ __launch_bounds__(256) void k_gemm(
    const _Float16* __restrict__ A,   // [M][512] f16
    const _Float16* __restrict__ BT,  // [1536][512] f16
    const float* __restrict__ b2, const float* __restrict__ b3,
    _Float16* __restrict__ support, float* __restrict__ trans,
    _Float16* __restrict__ gate, int M)
{
  constexpr int LSTR = 40;  // 32 + 8 pad (16B) -> <=2-way bank aliasing (free)
  __shared__ __align__(16) _Float16 ldsA[128 * LSTR];
  __shared__ __align__(16) _Float16 ldsB[128 * LSTR];
  int t = threadIdx.x;
  int colBase = blockIdx.x * 128;
  int rowBase = blockIdx.y * 128;
  int w = t >> 6, lane = t & 63, lr = lane & 15, quad = lane >> 4;
  int wrow = (w >> 1) * 64, wcol = (w & 1) * 64;
  floatx4 acc[4][4] = {};
  int srow = t >> 2;        // 0..63
  int skk = (t & 3) * 8;    // 0,8,16,24

  for (int k0 = 0; k0 < D; k0 += 32) {
#pragma unroll
    for (int rep = 0; rep < 2; ++rep) {
      int row = srow + rep * 64;
      int gr = rowBase + row;
      uint4 av = make_uint4(0, 0, 0, 0);
      if (gr < M) av = *(const uint4*)(A + gr * D + k0 + skk);
      *(uint4*)(&ldsA[row * LSTR + skk]) = av;
      uint4 bv = *(const uint4*)(BT + (colBase + row) * D + k0 + skk);
      *(uint4*)(&ldsB[row * LSTR + skk]) = bv;
    }
    __syncthreads();
    half8 af[4], bf[4];
#pragma unroll
    for (int i2 = 0; i2 < 4; ++i2)
      af[i2] = *(const half8*)(&ldsA[(wrow + i2 * 16 + lr) * LSTR + quad * 8]);
#pragma unroll
    for (int j = 0; j < 4; ++j)
      bf[j] = *(const half8*)(&ldsB[(wcol + j * 16 + lr) * LSTR + quad * 8]);
#pragma unroll
    for (int i2 = 0; i2 < 4; ++i2)
#pragma unroll
      for (int j = 0; j < 4; ++j)
        acc[i2][j] = __builtin_amdgcn_mfma_f32_16x16x32_f16(af[i2], bf[j], acc[i2][j], 0, 0, 0);
    __syncthreads();
  }

  // C/D layout: col = lane&15, row = quad*4 + reg  [verified mapping]
#pragma unroll
  for (int i2 = 0; i2 < 4; ++i2) {
    int r0 = rowBase + wrow + i2 * 16 + quad * 4;
#pragma unroll
    for (int j = 0; j < 4; ++j) {
      int c = colBase + wcol + j * 16 + lr;
#pragma unroll
      for (int rg = 0; rg < 4; ++rg) {
        int r = r0 + rg;
        if (r >= M) continue;
        float v = acc[i2][j][rg];
        if (c < D) {
          support[r * D + c] = (_Float16)v;
        } else if (c < 2 * D) {
          trans[r * D + (c - D)] = v + b2[c - D];
        } else {
          int cc = c - 2 * D;
          float gv = v + b3[cc];
          gv = 1.0f / (1.0f + __expf(-gv));
          gate[r * D + cc] = (_Float16)gv;
        }
      }
    }
  }
}

// ---------------- aggregation + fused epilogue ----------------
// one wave per node; lane handles 8 channels (16B f16 loads).
// out[] holds trans on entry, final result on exit.
__global__ __launch_bounds__(256) void k_agg(
    const _Float16* __restrict__ support, const _Float16* __restrict__ gate,
    float* __restrict__ out, const float* __restrict__ b1,
    const int* __restrict__ offsets, const int2* __restrict__ edges, int n)
{
  int wid = (blockIdx.x * 256 + threadIdx.x) >> 6;
  if (wid >= n) return;
  int lane = threadIdx.x & 63;
  int s = offsets[wid], e = offsets[wid + 1];
  float acc[8] = {0, 0, 0, 0, 0, 0, 0, 0};
  const half8* sup8 = (const half8*)support;
  int i = s;
  for (; i + 2 <= e; i += 2) {   // 2-deep for independent outstanding loads
    int2 c0 = edges[i];
    int2 c1 = edges[i + 1];
    half8 h0 = sup8[c0.x * 64 + lane];
    half8 h1 = sup8[c1.x * 64 + lane];
    float v0 = __int_as_float(c0.y), v1 = __int_as_float(c1.y);
#pragma unroll
    for (int j = 0; j < 8; ++j) acc[j] += v0 * (float)h0[j] + v1 * (float)h1[j];
  }
  if (i < e) {
    int2 c0 = edges[i];
    half8 h0 = sup8[c0.x * 64 + lane];
    float v0 = __int_as_float(c0.y);
#pragma unroll
    for (int j = 0; j < 8; ++j) acc[j] += v0 * (float)h0[j];
  }
  int base = wid * 128 + lane * 2;  // float4 units
  float4 t0 = ((const float4*)out)[base];
  float4 t1 = ((const float4*)out)[base + 1];
  half8 g = ((const half8*)gate)[wid * 64 + lane];
  float4 bb0 = ((const float4*)b1)[lane * 2];
  float4 bb1 = ((const float4*)b1)[lane * 2 + 1];
  float tt[8]  = {t0.x, t0.y, t0.z, t0.w, t1.x, t1.y, t1.z, t1.w};
  float bbv[8] = {bb0.x, bb0.y, bb0.z, bb0.w, bb1.x, bb1.y, bb1.z, bb1.w};
  float res[8];
#pragma unroll
  for (int j = 0; j < 8; ++j) {
    float o = acc[j] + bbv[j];
    o = o > 0.f ? o : 0.f;
    res[j] = tt[j] + (float)g[j] * (o - tt[j]);
  }
  ((float4*)out)[base]     = make_float4(res[0], res[1], res[2], res[3]);
  ((float4*)out)[base + 1] = make_float4(res[4], res[5], res[6], res[7]);
}

// ---------------- launch ----------------

extern "C" void kernel_launch(void* const* d_in, const int* in_sizes, int n_in,
                              void* d_out, int out_size, void* d_ws, size_t ws_size,
                              hipStream_t stream) {
  const float* x    = (const float*)d_in[0];
  const float* w1   = (const float*)d_in[1];
  const float* w2   = (const float*)d_in[2];
  const float* w3   = (const float*)d_in[3];
  const float* b1   = (const float*)d_in[4];
  const float* b2   = (const float*)d_in[5];
  const float* b3   = (const float*)d_in[6];
  const int*   erow = (const int*)d_in[7];
  const int*   ecol = (const int*)d_in[8];
  const float* eval = (const float*)d_in[9];
  float* out = (float*)d_out;

  int N = in_sizes[0] / D;  // 100000
  int E = in_sizes[7];      // 3200000

  char* ws = (char*)d_ws;
  size_t off = 0;
  auto take = [&](size_t bytes) -> char* {
    char* p = ws + off;
    off += (bytes + 255) & ~(size_t)255;
    return p;
  };
  _Float16* xh    = (_Float16*)take((size_t)N * D * 2);
  _Float16* wT    = (_Float16*)take((size_t)3 * D * D * 2);
  _Float16* sup   = (_Float16*)take((size_t)N * D * 2);
  _Float16* gate  = (_Float16*)take((size_t)N * D * 2);
  int* counts     = (int*)take((size_t)N * 4);
  int* cursor     = (int*)take((size_t)N * 4);
  int* offsets    = (int*)take((size_t)(N + 1) * 4);
  int2* edges     = (int2*)take((size_t)E * 8);

  hipMemsetAsync(counts, 0, (size_t)N * 4, stream);
  hipMemsetAsync(cursor, 0, (size_t)N * 4, stream);

  int n4 = N * D / 4;
  k_f32_to_f16<<<(n4 + 255) / 256, 256, 0, stream>>>(x, xh, n4);
  k_build_wt<<<(3 * D * D + 255) / 256, 256, 0, stream>>>(w1, w2, w3, wT);
  k_count<<<(E + 255) / 256, 256, 0, stream>>>(erow, counts, E);
  k_scan<<<1, 1024, 0, stream>>>(counts, offsets, N);
  k_scatter<<<(E + 255) / 256, 256, 0, stream>>>(erow, ecol, eval, offsets, cursor, edges, E);
  dim3 gg(3 * D / 128, (N + 127) / 128);
  k_gemm<<<gg, 256, 0, stream>>>(xh, wT, b2, b3, sup, out, gate, N);
  k_agg<<<((size_t)N * 64 + 255) / 256, 256, 0, stream>>>(sup, gate, out, b1, offsets, edges, N);
}

// Round 2
// 1514.462 us; speedup vs baseline: 1.1121x; 1.1121x over previous
//
#include <hip/hip_runtime.h>
#include <hip/hip_bf16.h>
#include <hip/hip_fp16.h>

#define D 512

typedef _Float16 half8 __attribute__((ext_vector_type(8)));
typedef _Float16 half4v __attribute__((ext_vector_type(4)));
typedef float floatx4 __attribute__((ext_vector_type(4)));

// ---------------- conversion kernels ----------------

__global__ void k_f32_to_f16(const float* __restrict__ in, _Float16* __restrict__ out, int n4) {
  int i = blockIdx.x * blockDim.x + threadIdx.x;
  if (i >= n4) return;
  float4 v = ((const float4*)in)[i];
  half4v h;
  h.x = (_Float16)v.x; h.y = (_Float16)v.y; h.z = (_Float16)v.z; h.w = (_Float16)v.w;
  ((half4v*)out)[i] = h;
}

// wT[jg][k] = w_m[k][j],  jg = m*512 + j  (B^T layout for MFMA)
__global__ void k_build_wt(const float* __restrict__ w1, const float* __restrict__ w2,
                           const float* __restrict__ w3, _Float16* __restrict__ wT) {
  int id = blockIdx.x * blockDim.x + threadIdx.x;
  if (id >= 3 * D * D) return;
  int jg = id >> 9;
  int k  = id & (D - 1);
  const float* w = (jg < D) ? w1 : (jg < 2 * D ? w2 : w3);
  int j = jg & (D - 1);
  wT[id] = (_Float16)w[k * D + j];
}

// ---------------- CSR build ----------------

__global__ void k_count(const int* __restrict__ row, int* __restrict__ counts, int E) {
  int i = blockIdx.x * blockDim.x + threadIdx.x;
  if (i < E) atomicAdd(&counts[row[i]], 1);
}

// multi-block exclusive scan, phase 1: per-block (1024 elems) scan + block sums
__global__ __launch_bounds__(256) void k_scan1(const int* __restrict__ in, int* __restrict__ out,
                                               int* __restrict__ bsums, int n) {
  __shared__ int wsum[4];
  int t = threadIdx.x, lane = t & 63, wd = t >> 6;
  int i0 = blockIdx.x * 1024 + t * 4;
  int4 c = make_int4(0, 0, 0, 0);
  if (i0 + 3 < n) c = *(const int4*)(in + i0);
  else {
    if (i0 < n) c.x = in[i0];
    if (i0 + 1 < n) c.y = in[i0 + 1];
    if (i0 + 2 < n) c.z = in[i0 + 2];
  }
  int s1 = c.x, s2 = s1 + c.y, s3 = s2 + c.z, s4 = s3 + c.w;
  int x = s4;
#pragma unroll
  for (int o = 1; o < 64; o <<= 1) { int p = __shfl_up(x, o); if (lane >= o) x += p; }
  if (lane == 63) wsum[wd] = x;
  __syncthreads();
  int wex = 0;
  for (int k = 0; k < wd; ++k) wex += wsum[k];
  int base = wex + x - s4;
  if (i0 + 3 < n) *(int4*)(out + i0) = make_int4(base, base + s1, base + s2, base + s3);
  else {
    if (i0 < n) out[i0] = base;
    if (i0 + 1 < n) out[i0 + 1] = base + s1;
    if (i0 + 2 < n) out[i0 + 2] = base + s2;
  }
  if (t == 0) bsums[blockIdx.x] = wsum[0] + wsum[1] + wsum[2] + wsum[3];
}

// phase 2: single small block scans block sums (nb <= 128), writes grand total
__global__ void k_scan2(int* __restrict__ bsums, int* __restrict__ total_out, int nb) {
  __shared__ int w0;
  int t = threadIdx.x, lane = t & 63, wd = t >> 6;
  int v = (t < nb) ? bsums[t] : 0;
  int x = v;
#pragma unroll
  for (int o = 1; o < 64; o <<= 1) { int p = __shfl_up(x, o); if (lane >= o) x += p; }
  if (wd == 0 && lane == 63) w0 = x;
  __syncthreads();
  int excl = x - v + (wd ? w0 : 0);
  if (t < nb) bsums[t] = excl;
  if (t == 127) *total_out = w0 + x;
}

// phase 3: add scanned block sums
__global__ __launch_bounds__(256) void k_scan3(int* __restrict__ out, const int* __restrict__ bsums, int n) {
  int t = threadIdx.x;
  int i0 = blockIdx.x * 1024 + t * 4;
  int add = bsums[blockIdx.x];
  if (i0 + 3 < n) {
    int4 v = *(int4*)(out + i0);
    v.x += add; v.y += add; v.z += add; v.w += add;
    *(int4*)(out + i0) = v;
  } else {
    for (int k = 0; k < 4; ++k) if (i0 + k < n) out[i0 + k] += add;
  }
}

__global__ void k_scatter(const int* __restrict__ row, const int* __restrict__ col,
                          const float* __restrict__ val, const int* __restrict__ offsets,
                          int* __restrict__ cursor, int2* __restrict__ edges, int E) {
  int i = blockIdx.x * blockDim.x + threadIdx.x;
  if (i >= E) return;
  int r = row[i];
  int p = offsets[r] + atomicAdd(&cursor[r], 1);
  edges[p] = make_int2(col[i], __float_as_int(val[i]));
}

// ---------------- fused triple GEMM (m97-style: global_load_lds width=16) -------
// C = x @ [w1 | w2 | w3]; support=f16, trans=+b2 (fp32 -> d_out), gate=sigmoid(+b3) f16.
// 128x128 tile, 4 waves each 64x64. LDS chunk XOR-swizzle: stored chunk position
// c_store = chunk ^ ((row>>1)&3)  ->  ds_read_b128 aliasing <= 2-way (free).
__global__ __launch_bounds__(256) void k_gemm(
    const _Float16* __restrict__ A,   // [M][512] f16
    const _Float16* __restrict__ BT,  // [1536][512] f16
    const float* __restrict__ b2, const float* __restrict__ b3,
    _Float16* __restrict__ support, float* __restrict__ trans,
    _Float16* __restrict__ gate, int M)
{
  __shared__ __align__(16) _Float16 ldsA[128 * 32];
  __shared__ __align__(16) _Float16 ldsB[128 * 32];
  int t = threadIdx.x;
  int colBase = blockIdx.x * 128;
  int rowBase = blockIdx.y * 128;
  int w = t >> 6, lane = t & 63, lr = lane & 15, quad = lane >> 4;
  int wrow = (w >> 1) * 64, wcol = (w & 1) * 64;
  floatx4 acc[4][4] = {};

  // staging: wave w stages rows [w*32, w*32+32), 2 DMA calls x 16 rows x 64B
  int srow0 = w * 32 + (lane >> 2);
  int schunk = lane & 3;

  for (int k0 = 0; k0 < D; k0 += 32) {
#pragma unroll
    for (int c = 0; c < 2; ++c) {
      int srow = srow0 + c * 16;
      int chunk = schunk ^ ((srow >> 1) & 3);   // data chunk stored at this slot
      int ga = rowBase + srow; if (ga >= M) ga = M - 1;
      const _Float16* gA = A + (size_t)ga * D + k0 + chunk * 8;
      const _Float16* gB = BT + (size_t)(colBase + srow) * D + k0 + chunk * 8;
      _Float16* lA = &ldsA[(w * 32 + c * 16) * 32];
      _Float16* lB = &ldsB[(w * 32 + c * 16) * 32];
      __builtin_amdgcn_global_load_lds((const __attribute__((address_space(1))) void*)gA,
                                       (__attribute__((address_space(3))) void*)lA, 16, 0, 0);
      __builtin_amdgcn_global_load_lds((const __attribute__((address_space(1))) void*)gB,
                                       (__attribute__((address_space(3))) void*)lB, 16, 0, 0);
    }
    __syncthreads();
    half8 af[4], bf[4];
#pragma unroll
    for (int i2 = 0; i2 < 4; ++i2) {
      int r = wrow + i2 * 16 + lr;
      af[i2] = *(const half8*)&ldsA[r * 32 + ((quad ^ ((r >> 1) & 3)) << 3)];
    }
#pragma unroll
    for (int j = 0; j < 4; ++j) {
      int r = wcol + j * 16 + lr;
      bf[j] = *(const half8*)&ldsB[r * 32 + ((quad ^ ((r >> 1) & 3)) << 3)];
    }
#pragma unroll
    for (int i2 = 0; i2 < 4; ++i2)
#pragma unroll
      for (int j = 0; j < 4; ++j)
        acc[i2][j] = __builtin_amdgcn_mfma_f32_16x16x32_f16(af[i2], bf[j], acc[i2][j], 0, 0, 0);
    __syncthreads();
  }

  // C/D layout: col = lane&15, row = quad*4 + reg
#pragma unroll
  for (int i2 = 0; i2 < 4; ++i2) {
    int r0 = rowBase + wrow + i2 * 16 + quad * 4;
#pragma unroll
    for (int j = 0; j < 4; ++j) {
      int c = colBase + wcol + j * 16 + lr;
#pragma unroll
      for (int rg = 0; rg < 4; ++rg) {
        int r = r0 + rg;
        if (r >= M) continue;
        float v = acc[i2][j][rg];
        if (c < D) {
          support[(size_t)r * D + c] = (_Float16)v;
        } else if (c < 2 * D) {
          trans[(size_t)r * D + (c - D)] = v + b2[c - D];
        } else {
          int cc = c - 2 * D;
          float gv = v + b3[cc];
          gv = 1.0f / (1.0f + __expf(-gv));
          gate[(size_t)r * D + cc] = (_Float16)gv;
        }
      }
    }
  }
}

// ---------------- aggregation + fused epilogue ----------------
// one wave per node; lane handles 8 channels. Per 64-edge chunk: load one edge
// per lane, bitonic-sort by col in registers (locality: concurrent waves sweep
// support[] in a narrow col window -> L3-resident), then shfl-broadcast edges,
// gather 4-deep. out[] holds trans (fp32) on entry, final result on exit.
__global__ __launch_bounds__(256) void k_agg(
    const _Float16* __restrict__ support, const _Float16* __restrict__ gate,
    float* __restrict__ out, const float* __restrict__ b1,
    const int* __restrict__ offsets, const int2* __restrict__ edges, int n)
{
  int wid = (blockIdx.x * 256 + threadIdx.x) >> 6;
  if (wid >= n) return;
  int lane = threadIdx.x & 63;
  int s = offsets[wid], e = offsets[wid + 1];
  float acc[8] = {0, 0, 0, 0, 0, 0, 0, 0};
  const half8* sup8 = (const half8*)support;

  for (int base = s; base < e; base += 64) {
    int cnt = e - base; if (cnt > 64) cnt = 64;
    int key = 0x7fffffff; float val = 0.f;
    if (lane < cnt) {
      int2 ed = edges[base + lane];
      key = ed.x; val = __int_as_float(ed.y);
    }
    // 64-lane bitonic sort (key=col, payload=val)
#pragma unroll
    for (int size = 2; size <= 64; size <<= 1) {
#pragma unroll
      for (int stride = size >> 1; stride; stride >>= 1) {
        int pk = __shfl_xor(key, stride);
        float pv = __shfl_xor(val, stride);
        bool upper = (lane & stride) != 0;
        bool desc = (lane & size) != 0;
        bool takemax = upper != desc;
        bool swap = takemax ? (pk > key) : (pk < key);
        if (swap) { key = pk; val = pv; }
      }
    }
    int i = 0;
    for (; i + 4 <= cnt; i += 4) {
      int c0 = __shfl(key, i),     c1 = __shfl(key, i + 1);
      int c2 = __shfl(key, i + 2), c3 = __shfl(key, i + 3);
      float v0 = __shfl(val, i),     v1 = __shfl(val, i + 1);
      float v2 = __shfl(val, i + 2), v3 = __shfl(val, i + 3);
      half8 h0 = sup8[(size_t)c0 * 64 + lane];
      half8 h1 = sup8[(size_t)c1 * 64 + lane];
      half8 h2 = sup8[(size_t)c2 * 64 + lane];
      half8 h3 = sup8[(size_t)c3 * 64 + lane];
#pragma unroll
      for (int j = 0; j < 8; ++j)
        acc[j] += v0 * (float)h0[j] + v1 * (float)h1[j] + v2 * (float)h2[j] + v3 * (float)h3[j];
    }
    for (; i < cnt; ++i) {
      int c0 = __shfl(key, i);
      float v0 = __shfl(val, i);
      half8 h0 = sup8[(size_t)c0 * 64 + lane];
#pragma unroll
      for (int j = 0; j < 8; ++j) acc[j] += v0 * (float)h0[j];
    }
  }

  int base4 = wid * 128 + lane * 2;  // float4 units
  float4 t0 = ((const float4*)out)[base4];
  float4 t1 = ((const float4*)out)[base4 + 1];
  half8 g = ((const half8*)gate)[wid * 64 + lane];
  float4 bb0 = ((const float4*)b1)[lane * 2];
  float4 bb1 = ((const float4*)b1)[lane * 2 + 1];
  float tt[8]  = {t0.x, t0.y, t0.z, t0.w, t1.x, t1.y, t1.z, t1.w};
  float bbv[8] = {bb0.x, bb0.y, bb0.z, bb0.w, bb1.x, bb1.y, bb1.z, bb1.w};
  float res[8];
#pragma unroll
  for (int j = 0; j < 8; ++j) {
    float o = acc[j] + bbv[j];
    o = o > 0.f ? o : 0.f;
    res[j] = tt[j] + (float)g[j] * (o - tt[j]);
  }
  ((float4*)out)[base4]     = make_float4(res[0], res[1], res[2], res[3]);
  ((float4*)out)[base4 + 1] = make_float4(res[4], res[5], res[6], res[7]);
}

// ---------------- launch ----------------

extern "C" void kernel_launch(void* const* d_in, const int* in_sizes, int n_in,
                              void* d_out, int out_size, void* d_ws, size_t ws_size,
                              hipStream_t stream) {
  const float* x    = (const float*)d_in[0];
  const float* w1   = (const float*)d_in[1];
  const float* w2   = (const float*)d_in[2];
  const float* w3   = (const float*)d_in[3];
  const float* b1   = (const float*)d_in[4];
  const float* b2   = (const float*)d_in[5];
  const float* b3   = (const float*)d_in[6];
  const int*   erow = (const int*)d_in[7];
  const int*   ecol = (const int*)d_in[8];
  const float* eval = (const float*)d_in[9];
  float* out = (float*)d_out;

  int N = in_sizes[0] / D;  // 100000
  int E = in_sizes[7];      // 3200000

  char* ws = (char*)d_ws;
  size_t off = 0;
  auto take = [&](size_t bytes) -> char* {
    char* p = ws + off;
    off += (bytes + 255) & ~(size_t)255;
    return p;
  };
  _Float16* xh    = (_Float16*)take((size_t)N * D * 2);
  _Float16* wT    = (_Float16*)take((size_t)3 * D * D * 2);
  _Float16* sup   = (_Float16*)take((size_t)N * D * 2);
  _Float16* gate  = (_Float16*)take((size_t)N * D * 2);
  int* counts     = (int*)take((size_t)N * 4);
  int* cursor     = (int*)take((size_t)N * 4);
  int* offsets    = (int*)take((size_t)(N + 1) * 4);
  int* bsums      = (int*)take(128 * 4);
  int2* edges     = (int2*)take((size_t)E * 8);

  hipMemsetAsync(counts, 0, (size_t)N * 4, stream);
  hipMemsetAsync(cursor, 0, (size_t)N * 4, stream);

  int n4 = N * D / 4;
  k_f32_to_f16<<<(n4 + 255) / 256, 256, 0, stream>>>(x, xh, n4);
  k_build_wt<<<(3 * D * D + 255) / 256, 256, 0, stream>>>(w1, w2, w3, wT);
  k_count<<<(E + 255) / 256, 256, 0, stream>>>(erow, counts, E);
  int nb = (N + 1023) / 1024;
  k_scan1<<<nb, 256, 0, stream>>>(counts, offsets, bsums, N);
  k_scan2<<<1, 128, 0, stream>>>(bsums, offsets + N, nb);
  k_scan3<<<nb, 256, 0, stream>>>(offsets, bsums, N);
  k_scatter<<<(E + 255) / 256, 256, 0, stream>>>(erow, ecol, eval, offsets, cursor, edges, E);
  dim3 gg(3 * D / 128, (N + 127) / 128);
  k_gemm<<<gg, 256, 0, stream>>>(xh, wT, b2, b3, sup, out, gate, N);
  k_agg<<<((size_t)N * 64 + 255) / 256, 256, 0, stream>>>(sup, gate, out, b1, offsets, edges, N);
}